// Round 1
// baseline (331.308 us; speedup 1.0000x reference)
//
#include <hip/hip_runtime.h>

#define NSEQ 2048
#define DIMM 1024
#define NH   16
#define DH   64

using f32x4 = __attribute__((ext_vector_type(4))) float;
using s16x8 = __attribute__((ext_vector_type(8))) short;
using s16x4 = __attribute__((ext_vector_type(4))) short;

__device__ __forceinline__ short f2bf(float f) {
  union { float f; unsigned u; } a; a.f = f;
  unsigned r = (a.u + 0x7fffu + ((a.u >> 16) & 1u)) >> 16;
  return (short)(unsigned short)r;
}
__device__ __forceinline__ float bf2f(short s) {
  union { float f; unsigned u; } a; a.u = ((unsigned)(unsigned short)s) << 16;
  return a.f;
}

__device__ __forceinline__ void async_lds16(const void* g, void* l) {
  __builtin_amdgcn_global_load_lds(
      (const __attribute__((address_space(1))) void*)g,
      (__attribute__((address_space(3))) void*)l, 16, 0, 0);
}

__device__ __forceinline__ float wave_sum(float v) {
  v += __shfl_xor(v, 1);  v += __shfl_xor(v, 2);  v += __shfl_xor(v, 4);
  v += __shfl_xor(v, 8);  v += __shfl_xor(v, 16); v += __shfl_xor(v, 32);
  return v;
}

// ---------------- transpose + f32->bf16 convert: W (K x N) -> Wt (N x K) ----
__global__ __launch_bounds__(256) void transpose_w(const float* __restrict__ W,
                                                   short* __restrict__ Wt,
                                                   int K, int N) {
  __shared__ float tile[32][33];
  const int n0 = blockIdx.x * 32, k0 = blockIdx.y * 32;
  const int tx = threadIdx.x & 31, ty = threadIdx.x >> 5;   // ty: 0..7
#pragma unroll
  for (int r = 0; r < 32; r += 8)
    tile[ty + r][tx] = W[(size_t)(k0 + ty + r) * N + n0 + tx];
  __syncthreads();
#pragma unroll
  for (int r = 0; r < 32; r += 8)
    Wt[(size_t)(n0 + ty + r) * K + k0 + tx] = f2bf(tile[tx][ty + r]);
}

// ---------------- row LayerNorm over 1024 cols (+optional SiLU) -------------
template <bool SILU, bool OUTBF>
__global__ __launch_bounds__(256) void row_ln_k(const float* __restrict__ in,
                                                const float* __restrict__ gamma,
                                                float* __restrict__ of,
                                                short* __restrict__ ob) {
  const int r = blockIdx.x, t = threadIdx.x;
  float4 x = *(const float4*)(in + (size_t)r * 1024 + t * 4);
  float v[4] = {x.x, x.y, x.z, x.w};
  float s  = v[0] + v[1] + v[2] + v[3];
  float ss = v[0]*v[0] + v[1]*v[1] + v[2]*v[2] + v[3]*v[3];
  s = wave_sum(s); ss = wave_sum(ss);
  __shared__ float rb[8];
  const int w = t >> 6, ln = t & 63;
  if (ln == 0) { rb[w] = s; rb[4 + w] = ss; }
  __syncthreads();
  s  = rb[0] + rb[1] + rb[2] + rb[3];
  ss = rb[4] + rb[5] + rb[6] + rb[7];
  const float mean = s * (1.f / 1024.f);
  const float inv  = rsqrtf(ss * (1.f / 1024.f) - mean * mean + 1e-5f);
  float4 gx = *(const float4*)(gamma + t * 4);
  float gg[4] = {gx.x, gx.y, gx.z, gx.w};
#pragma unroll
  for (int j = 0; j < 4; j++) {
    float y = (v[j] - mean) * inv * gg[j];
    if (SILU) y = y / (1.f + __expf(-y));
    v[j] = y;
  }
  if (OUTBF) {
    s16x4 o;
#pragma unroll
    for (int j = 0; j < 4; j++) o[j] = f2bf(v[j]);
    *(s16x4*)(ob + (size_t)r * 1024 + t * 4) = o;
  } else {
    *(float4*)(of + (size_t)r * 1024 + t * 4) = make_float4(v[0], v[1], v[2], v[3]);
  }
}

// ---------------- bias-MLP layer 0: silu(ln(pos*w0 + b0, g0)), pos = row ----
__global__ __launch_bounds__(256) void layer0_k(const float* __restrict__ w0,
                                                const float* __restrict__ b0,
                                                const float* __restrict__ g0,
                                                short* __restrict__ h0) {
  const int r = blockIdx.x, t = threadIdx.x;
  const float p = (float)r;
  float4 wv = *(const float4*)(w0 + t * 4);
  float4 bv = *(const float4*)(b0 + t * 4);
  float v[4] = {p * wv.x + bv.x, p * wv.y + bv.y, p * wv.z + bv.z, p * wv.w + bv.w};
  float s  = v[0] + v[1] + v[2] + v[3];
  float ss = v[0]*v[0] + v[1]*v[1] + v[2]*v[2] + v[3]*v[3];
  s = wave_sum(s); ss = wave_sum(ss);
  __shared__ float rb[8];
  const int w = t >> 6, ln = t & 63;
  if (ln == 0) { rb[w] = s; rb[4 + w] = ss; }
  __syncthreads();
  s  = rb[0] + rb[1] + rb[2] + rb[3];
  ss = rb[4] + rb[5] + rb[6] + rb[7];
  const float mean = s * (1.f / 1024.f);
  const float inv  = rsqrtf(ss * (1.f / 1024.f) - mean * mean + 1e-5f);
  float4 gx = *(const float4*)(g0 + t * 4);
  float gg[4] = {gx.x, gx.y, gx.z, gx.w};
  s16x4 o;
#pragma unroll
  for (int j = 0; j < 4; j++) {
    float y = (v[j] - mean) * inv * gg[j];
    y = y / (1.f + __expf(-y));
    o[j] = f2bf(y);
  }
  *(s16x4*)(h0 + (size_t)r * 1024 + t * 4) = o;
}

// ---------------- q post: l2norm per 64-group * q_scale -> bf16 -------------
__global__ __launch_bounds__(64) void post_q(const float* __restrict__ qt,
                                             const float* __restrict__ qs,
                                             short* __restrict__ qb) {
  const int g = blockIdx.x, d = threadIdx.x;
  float v = qt[(size_t)g * 64 + d];
  float ss = wave_sum(v * v);
  float n = fmaxf(sqrtf(ss), 1e-12f);
  qb[(size_t)g * 64 + d] = f2bf(v / n * qs[d]);
}

// ---------------- kv post: k=l2norm*k_scale -> bf16, v -> v^T bf16 ----------
__global__ __launch_bounds__(128) void post_kv(const float* __restrict__ kvt,
                                               const float* __restrict__ ks,
                                               short* __restrict__ kb,
                                               short* __restrict__ vtb) {
  const int row = blockIdx.x, t = threadIdx.x;
  float v = kvt[(size_t)row * 128 + t];
  if (t < 64) {
    float ss = wave_sum(v * v);
    float n = fmaxf(sqrtf(ss), 1e-12f);
    kb[(size_t)row * 64 + t] = f2bf(v / n * ks[t]);
  } else {
    const int d = t - 64, b_ = row >> 11, i = row & 2047;
    vtb[((size_t)b_ * 64 + d) * NSEQ + i] = f2bf(v);
  }
}

// ---------------- btab: h1 (2048x1024 bf16) @ w2 (1024x16) + b2 -> [16][2048]
__global__ __launch_bounds__(256) void btab_k(const short* __restrict__ h1,
                                              const float* __restrict__ w2,
                                              const float* __restrict__ b2,
                                              float* __restrict__ btab) {
  const int r = blockIdx.x, t = threadIdx.x;
  const int n = t & 15, ck = t >> 4;    // 16 chunks of 64
  float acc = 0.f;
  const short* hrow = h1 + (size_t)r * 1024 + ck * 64;
  const float* wcol = w2 + (size_t)(ck * 64) * 16 + n;
#pragma unroll 8
  for (int k = 0; k < 64; k++) acc += bf2f(hrow[k]) * wcol[k * 16];
  __shared__ float red[256];
  red[t] = acc;
  __syncthreads();
  if (t < 16) {
    float s = 0.f;
#pragma unroll
    for (int c = 0; c < 16; c++) s += red[c * 16 + t];
    btab[(size_t)t * NSEQ + r] = s + b2[t];
  }
}

// ---------------- GEMM: C(MxN f32) = A(MxK bf16) * B^T where Bm is (NxK bf16)
template <bool ADD_BIAS>
__global__ __launch_bounds__(256, 2) void gemm_bt(const short* __restrict__ A,
                                                  const short* __restrict__ Bm,
                                                  float* __restrict__ C,
                                                  const float* __restrict__ bias,
                                                  int M, int N, int K) {
  __shared__ __align__(16) short Al[128 * 32];
  __shared__ __align__(16) short Bl[128 * 32];
  const int tid = threadIdx.x;
  const int lane = tid & 63;
  const int l15 = lane & 15, l4 = lane >> 4;
  const int wid = tid >> 6;
  const int wr = wid >> 1, wc = wid & 1;
  const int rowa0 = blockIdx.x * 128, rowb0 = blockIdx.y * 128;
  f32x4 acc[4][4];
#pragma unroll
  for (int m = 0; m < 4; m++)
#pragma unroll
    for (int n = 0; n < 4; n++) acc[m][n] = (f32x4){0.f, 0.f, 0.f, 0.f};

  const int sr = tid >> 2, sc = (tid & 3) * 8;        // staging row / col
  const short* ga = A  + (size_t)(rowa0 + sr) * K + sc;
  const short* gb = Bm + (size_t)(rowb0 + sr) * K + sc;
  char* la = (char*)Al + wid * 1024;                  // wave-uniform LDS base
  char* lb = (char*)Bl + wid * 1024;

  for (int k0 = 0; k0 < K; k0 += 32) {
    async_lds16(ga + k0,                 la);
    async_lds16(ga + (size_t)64 * K + k0, la + 4096);
    async_lds16(gb + k0,                 lb);
    async_lds16(gb + (size_t)64 * K + k0, lb + 4096);
    __syncthreads();
    s16x8 af[4], bfr[4];
#pragma unroll
    for (int m = 0; m < 4; m++)
      af[m] = *(const s16x8*)&Al[(wr * 64 + m * 16 + l15) * 32 + l4 * 8];
#pragma unroll
    for (int n = 0; n < 4; n++)
      bfr[n] = *(const s16x8*)&Bl[(wc * 64 + n * 16 + l15) * 32 + l4 * 8];
#pragma unroll
    for (int m = 0; m < 4; m++)
#pragma unroll
      for (int n = 0; n < 4; n++)
        acc[m][n] = __builtin_amdgcn_mfma_f32_16x16x32_bf16(af[m], bfr[n], acc[m][n], 0, 0, 0);
    __syncthreads();
  }
#pragma unroll
  for (int n = 0; n < 4; n++) {
    const int col = rowb0 + wc * 64 + n * 16 + l15;
    const float bv = ADD_BIAS ? bias[col] : 0.f;
#pragma unroll
    for (int m = 0; m < 4; m++) {
      const int row = rowa0 + wr * 64 + m * 16 + l4 * 4;
#pragma unroll
      for (int j = 0; j < 4; j++)
        C[(size_t)(row + j) * N + col] = acc[m][n][j] + bv;
    }
  }
}

// ---------------- flash attention with null token + rel-pos bias ------------
__global__ __launch_bounds__(256, 2) void attn_k(const short* __restrict__ q,
                                                 const short* __restrict__ kk,
                                                 const short* __restrict__ vt,
                                                 const float* __restrict__ btab,
                                                 const float* __restrict__ nkv,
                                                 const float* __restrict__ nbias,
                                                 const float* __restrict__ kscale,
                                                 short* __restrict__ aout) {
  __shared__ __align__(16) short Kl[64 * 64];     // [key][d], 16B-blk XOR swizzled
  __shared__ __align__(16) short Vl[64 * 64];     // [d][key], swizzled
  __shared__ __align__(16) short Pl[4 * 16 * 64]; // per-wave P, swizzled
  __shared__ __align__(16) float Ob[4 * 16 * 64]; // per-wave O for coalesced store
  __shared__ float nkn[64], nvv[64];

  const int tid = threadIdx.x;
  const int w = tid >> 6, lane = tid & 63;
  const int l15 = lane & 15, l4 = lane >> 4;
  const int i0 = blockIdx.x * 64, h = blockIdx.y, b = blockIdx.z;
  const int qrow0 = i0 + w * 16;

  if (w == 0) {
    float kx = nkv[lane];
    float ss = wave_sum(kx * kx);
    float nrm = fmaxf(sqrtf(ss), 1e-12f);
    nkn[lane] = kx / nrm * kscale[lane];
    nvv[lane] = nkv[64 + lane];
  }
  const short* qbase = q + (size_t)(b * NSEQ + qrow0) * DIMM + h * DH;
  s16x8 qf0 = *(const s16x8*)(qbase + (size_t)l15 * DIMM + l4 * 8);
  s16x8 qf1 = *(const s16x8*)(qbase + (size_t)l15 * DIMM + 32 + l4 * 8);
  __syncthreads();

  // null-token init of online softmax
  float sn = 0.f;
#pragma unroll
  for (int j = 0; j < 8; j++)
    sn += bf2f(qf0[j]) * nkn[l4 * 8 + j] + bf2f(qf1[j]) * nkn[32 + l4 * 8 + j];
  sn += __shfl_xor(sn, 16);
  sn += __shfl_xor(sn, 32);
  sn = sn * 8.f + nbias[h];
  float mrow[4], lsum[4];
  f32x4 o[4];
#pragma unroll
  for (int jj = 0; jj < 4; jj++) { mrow[jj] = __shfl(sn, l4 * 4 + jj); lsum[jj] = 1.f; }
#pragma unroll
  for (int dg = 0; dg < 4; dg++) {
    float nv = nvv[dg * 16 + l15];
#pragma unroll
    for (int jj = 0; jj < 4; jj++) o[dg][jj] = nv;
  }

  const float* bth = btab + (size_t)h * NSEQ;
  const int nt = blockIdx.x + 1;
  const int sr = tid >> 3;                      // staging row (0..31)
  const int sb = (tid & 7) ^ (sr & 7);          // pre-swizzled source block
  const short* gk = kk + ((size_t)(b * NSEQ) + sr) * DH + sb * 8;
  const short* gv = vt + ((size_t)b * DH + sr) * NSEQ + sb * 8;
  char* lK = (char*)Kl + w * 1024;
  char* lV = (char*)Vl + w * 1024;
  char* pw = (char*)Pl + w * 2048;

  for (int t = 0; t < nt; ++t) {
    const int j0 = t * 64;
    async_lds16(gk + (size_t)j0 * DH,        lK);
    async_lds16(gk + (size_t)(j0 + 32) * DH, lK + 4096);
    async_lds16(gv + j0,                     lV);
    async_lds16(gv + 32 * NSEQ + j0,         lV + 4096);
    __syncthreads();

    f32x4 s[4];
#pragma unroll
    for (int kb = 0; kb < 4; kb++) s[kb] = (f32x4){0.f, 0.f, 0.f, 0.f};
#pragma unroll
    for (int c = 0; c < 2; c++) {
#pragma unroll
      for (int kb = 0; kb < 4; kb++) {
        const int key = kb * 16 + l15;
        s16x8 kf = *(const s16x8*)((const char*)Kl + key * 128 +
                                   ((((c << 2) + l4) ^ (key & 7)) << 4));
        s[kb] = __builtin_amdgcn_mfma_f32_16x16x32_bf16(c == 0 ? qf0 : qf1, kf, s[kb], 0, 0, 0);
      }
    }
    float pm[4] = {-3e38f, -3e38f, -3e38f, -3e38f};
#pragma unroll
    for (int kb = 0; kb < 4; kb++) {
      const int keyg = j0 + kb * 16 + l15;
#pragma unroll
      for (int jj = 0; jj < 4; jj++) {
        const int i = i0 + w * 16 + l4 * 4 + jj;
        const int rel = i - keyg;
        float sv = (rel >= 0) ? (s[kb][jj] * 8.f + bth[rel]) : -3e38f;
        s[kb][jj] = sv;
        pm[jj] = fmaxf(pm[jj], sv);
      }
    }
#pragma unroll
    for (int jj = 0; jj < 4; jj++) {
      pm[jj] = fmaxf(pm[jj], __shfl_xor(pm[jj], 1));
      pm[jj] = fmaxf(pm[jj], __shfl_xor(pm[jj], 2));
      pm[jj] = fmaxf(pm[jj], __shfl_xor(pm[jj], 4));
      pm[jj] = fmaxf(pm[jj], __shfl_xor(pm[jj], 8));
    }
    float al[4], rs[4];
#pragma unroll
    for (int jj = 0; jj < 4; jj++) {
      const float mn = fmaxf(mrow[jj], pm[jj]);
      al[jj] = __expf(mrow[jj] - mn);
      mrow[jj] = mn;
      rs[jj] = 0.f;
    }
#pragma unroll
    for (int kb = 0; kb < 4; kb++)
#pragma unroll
      for (int jj = 0; jj < 4; jj++) {
        const float p = __expf(s[kb][jj] - mrow[jj]);
        s[kb][jj] = p;
        rs[jj] += p;
      }
#pragma unroll
    for (int jj = 0; jj < 4; jj++) {
      rs[jj] += __shfl_xor(rs[jj], 1);
      rs[jj] += __shfl_xor(rs[jj], 2);
      rs[jj] += __shfl_xor(rs[jj], 4);
      rs[jj] += __shfl_xor(rs[jj], 8);
      lsum[jj] = lsum[jj] * al[jj] + rs[jj];
    }
#pragma unroll
    for (int dg = 0; dg < 4; dg++)
#pragma unroll
      for (int jj = 0; jj < 4; jj++) o[dg][jj] *= al[jj];
    // P: C-layout -> swizzled LDS [row=q][key]
#pragma unroll
    for (int kb = 0; kb < 4; kb++) {
      const int key = kb * 16 + l15;
#pragma unroll
      for (int jj = 0; jj < 4; jj++) {
        const int row = l4 * 4 + jj;
        *(short*)(pw + row * 128 + (((key >> 3) ^ (row & 7)) << 4) + ((key & 7) << 1)) =
            f2bf(s[kb][jj]);
      }
    }
    __syncthreads();
#pragma unroll
    for (int kc = 0; kc < 2; kc++) {
      s16x8 pf = *(const s16x8*)(pw + l15 * 128 + ((((kc << 2) + l4) ^ (l15 & 7)) << 4));
#pragma unroll
      for (int dg = 0; dg < 4; dg++) {
        const int d = dg * 16 + l15;
        s16x8 vf = *(const s16x8*)((const char*)Vl + d * 128 +
                                   ((((kc << 2) + l4) ^ (d & 7)) << 4));
        o[dg] = __builtin_amdgcn_mfma_f32_16x16x32_bf16(pf, vf, o[dg], 0, 0, 0);
      }
    }
    __syncthreads();
  }

  float* ob = Ob + w * 1024;
#pragma unroll
  for (int dg = 0; dg < 4; dg++)
#pragma unroll
    for (int jj = 0; jj < 4; jj++)
      ob[(l4 * 4 + jj) * 64 + dg * 16 + l15] = o[dg][jj] / lsum[jj];
  __syncthreads();
  const int orow = lane >> 2, oc = (lane & 3) * 16;
  const float* srcp = ob + orow * 64 + oc;
  s16x8 r0, r1;
#pragma unroll
  for (int j = 0; j < 8; j++) { r0[j] = f2bf(srcp[j]); r1[j] = f2bf(srcp[8 + j]); }
  short* gout = aout + (size_t)(b * NSEQ + i0 + w * 16 + orow) * DIMM + h * DH + oc;
  *(s16x8*)gout = r0;
  *(s16x8*)(gout + 8) = r1;
}

// ---------------------------------------------------------------------------
extern "C" void kernel_launch(void* const* d_in, const int* in_sizes, int n_in,
                              void* d_out, int out_size, void* d_ws, size_t ws_size,
                              hipStream_t stream) {
  const float* x       = (const float*)d_in[0];
  const float* g_norm  = (const float*)d_in[2];
  const float* Wq      = (const float*)d_in[3];
  const float* Wkv     = (const float*)d_in[4];
  const float* q_scale = (const float*)d_in[5];
  const float* k_scale = (const float*)d_in[6];
  const float* null_kv = (const float*)d_in[7];
  const float* nbias   = (const float*)d_in[8];
  const float* w0      = (const float*)d_in[9];
  const float* b0      = (const float*)d_in[10];
  const float* g0      = (const float*)d_in[11];
  const float* w1      = (const float*)d_in[12];
  const float* b1      = (const float*)d_in[13];
  const float* g1      = (const float*)d_in[14];
  const float* w2      = (const float*)d_in[15];
  const float* b2      = (const float*)d_in[16];
  const float* Wout    = (const float*)d_in[17];
  const float* g_out   = (const float*)d_in[18];

  char* p = (char*)d_ws;
  auto alloc = [&](size_t bytes) {
    char* r = p; p += (bytes + 255) & ~(size_t)255; return r;
  };
  short* xn   = (short*)alloc((size_t)4096 * 1024 * 2);
  short* wqT  = (short*)alloc((size_t)1024 * 1024 * 2);
  short* wkvT = (short*)alloc((size_t)128 * 1024 * 2);
  short* w1T  = (short*)alloc((size_t)1024 * 1024 * 2);
  short* woT  = (short*)alloc((size_t)1024 * 1024 * 2);
  float* qtmp = (float*)alloc((size_t)4096 * 1024 * 4);
  float* kvtmp= (float*)alloc((size_t)4096 * 128 * 4);
  short* qb   = (short*)alloc((size_t)4096 * 1024 * 2);
  short* kbuf = (short*)alloc((size_t)2 * NSEQ * DH * 2);
  short* vtb  = (short*)alloc((size_t)2 * DH * NSEQ * 2);
  short* h0   = (short*)alloc((size_t)2048 * 1024 * 2);
  short* h1   = (short*)alloc((size_t)2048 * 1024 * 2);
  float* btab = (float*)alloc((size_t)16 * NSEQ * 4);
  float* h1t  = qtmp;          // reuse: qtmp consumed by post_q before h1t written
  float* opre = qtmp;          // reuse again after h1t consumed
  short* aout = xn;            // reuse: xn consumed by the two input GEMMs

  // weight transposes (f32 -> bf16, N x K)
  transpose_w<<<dim3(32, 32), 256, 0, stream>>>(Wq,   wqT,  1024, 1024);
  transpose_w<<<dim3(4, 32),  256, 0, stream>>>(Wkv,  wkvT, 1024, 128);
  transpose_w<<<dim3(32, 32), 256, 0, stream>>>(w1,   w1T,  1024, 1024);
  transpose_w<<<dim3(32, 32), 256, 0, stream>>>(Wout, woT,  1024, 1024);
  // xn = LN(x) * g_norm  -> bf16
  row_ln_k<false, true><<<4096, 256, 0, stream>>>(x, g_norm, nullptr, xn);
  // q / kv projections
  gemm_bt<false><<<dim3(32, 8), 256, 0, stream>>>(xn, wqT,  qtmp,  nullptr, 4096, 1024, 1024);
  gemm_bt<false><<<dim3(32, 1), 256, 0, stream>>>(xn, wkvT, kvtmp, nullptr, 4096, 128, 1024);
  post_q<<<65536, 64, 0, stream>>>(qtmp, q_scale, qb);
  post_kv<<<4096, 128, 0, stream>>>(kvtmp, k_scale, kbuf, vtb);
  // rel-pos bias MLP (only rel in [0,2047] is ever used)
  layer0_k<<<2048, 256, 0, stream>>>(w0, b0, g0, h0);
  gemm_bt<true><<<dim3(16, 8), 256, 0, stream>>>(h0, w1T, h1t, b1, 2048, 1024, 1024);
  row_ln_k<true, true><<<2048, 256, 0, stream>>>(h1t, g1, nullptr, h1);
  btab_k<<<2048, 256, 0, stream>>>(h1, w2, b2, btab);
  // flash attention
  attn_k<<<dim3(32, NH, 2), 256, 0, stream>>>(qb, kbuf, vtb, btab, null_kv, nbias,
                                              k_scale, aout);
  // output projection + final LN
  gemm_bt<false><<<dim3(32, 8), 256, 0, stream>>>(aout, woT, opre, nullptr, 4096, 1024, 1024);
  row_ln_k<false, false><<<4096, 256, 0, stream>>>(opre, g_out, (float*)d_out, nullptr);
}